// Round 18
// baseline (429.599 us; speedup 1.0000x reference)
//
#include <hip/hip_runtime.h>

#define U_NUM 100000
#define NE    1600000
#define SEQL  5

// ws layout (bytes)
#define OFF_DEG      0UL         // int[100000]
#define OFF_ROWSTART 800000UL    // int[100001]
#define OFF_DINV     1200016UL   // float[100000]
#define OFF_BSUM     1600016UL   // int[128]
#define OFF_CSR      1600528UL   // int[1600000]
#define OFF_XS       8000528UL   // bf16-packed uint[3200000] (12.8MB); bins overlay pre-gemm
#define OFF_B        20800528UL  // float[6400000] (25.6MB); attn rewrites as [uef|ci2s] bf16 records
#define OFF_CCP      46400528UL  // u32x2[1600000]: paired {ci,ci2} bf16 rows (12.8MB, end 59200528)

// edge binning (bins overlay XS region; dead before k_gemm64_mfma writes XS)
#define NB    196
#define BSH   9
#define BCAP  12240
#define OFF_BINS  OFF_XS
#define OFF_GCUR  (OFF_BINS + (size_t)NB * BCAP * 8)

typedef __attribute__((ext_vector_type(8))) short bf16x8;
typedef __attribute__((ext_vector_type(4))) float f32x4;
typedef __attribute__((ext_vector_type(2))) unsigned u32x2;

__device__ __forceinline__ float rd_lane(float v, int l) {
    return __int_as_float(__builtin_amdgcn_readlane(__float_as_int(v), l));
}

__device__ __forceinline__ short f2bf(float f) {
    unsigned u = __float_as_uint(f);
    unsigned r = (u + 0x7fffu + ((u >> 16) & 1u)) >> 16;
    return (short)r;
}

__device__ __forceinline__ unsigned pk2(float a, float b) {
    return ((unsigned)(unsigned short)f2bf(a)) | (((unsigned)(unsigned short)f2bf(b)) << 16);
}

__device__ __forceinline__ float bflo(unsigned p) { return __uint_as_float(p << 16); }
__device__ __forceinline__ float bfhi(unsigned p) { return __uint_as_float(p & 0xffff0000u); }

// swizzled byte offset within a row-major LDS tile (T2: XOR bits 4-6 by row&7)
__device__ __forceinline__ int swzo(int row, int bytecol, int rowstride) {
    return row * rowstride + (bytecol ^ ((row & 7) << 4));
}

__global__ __launch_bounds__(256) void k_count(const int* __restrict__ edge, int* __restrict__ deg) {
    int e = blockIdx.x * 256 + threadIdx.x;
    atomicAdd(&deg[edge[NE + e]], 1);
}

__global__ __launch_bounds__(256) void k_dinv(const int* __restrict__ deg, float* __restrict__ dinv) {
    int i = blockIdx.x * 256 + threadIdx.x;
    if (i < U_NUM) dinv[i] = rsqrtf((float)(deg[i] + 1));
}

// paired conversion: CCP[i] = {pk2(ci[2i],ci[2i+1]), pk2(ci2[2i],ci2[2i+1])}, i over 1.6M
__global__ __launch_bounds__(256) void k_cvtP(const float* __restrict__ ci, const float* __restrict__ ci2,
                                              u32x2* __restrict__ ccp) {
    int i = blockIdx.x * 256 + threadIdx.x;
    float2 a = *(const float2*)(ci + (size_t)i * 2);
    float2 b = *(const float2*)(ci2 + (size_t)i * 2);
    u32x2 r;
    r.x = pk2(a.x, a.y);
    r.y = pk2(b.x, b.y);
    ccp[i] = r;
}

__global__ __launch_bounds__(1024) void k_scanA(const int* __restrict__ deg, int* __restrict__ bsum) {
    __shared__ int sm[1024];
    int i = blockIdx.x * 1024 + threadIdx.x;
    sm[threadIdx.x] = (i < U_NUM) ? deg[i] : 0;
    __syncthreads();
    for (int off = 512; off > 0; off >>= 1) {
        if (threadIdx.x < off) sm[threadIdx.x] += sm[threadIdx.x + off];
        __syncthreads();
    }
    if (threadIdx.x == 0) bsum[blockIdx.x] = sm[0];
}

__global__ void k_scanB(int* bsum, int nb) {
    if (threadIdx.x == 0) {
        int acc = 0;
        for (int b = 0; b < nb; ++b) { int v = bsum[b]; bsum[b] = acc; acc += v; }
    }
}

__global__ __launch_bounds__(1024) void k_scanC(const int* __restrict__ deg, const int* __restrict__ bsum,
                                                int* __restrict__ row_start) {
    __shared__ int sm[1024];
    int t = threadIdx.x;
    int i = blockIdx.x * 1024 + t;
    int v = (i < U_NUM) ? deg[i] : 0;
    sm[t] = v;
    __syncthreads();
    for (int off = 1; off < 1024; off <<= 1) {
        int x = (t >= off) ? sm[t - off] : 0;
        __syncthreads();
        sm[t] += x;
        __syncthreads();
    }
    int incl = sm[t];
    int base = bsum[blockIdx.x];
    if (i < U_NUM) row_start[i] = base + incl - v;
    if (i == U_NUM - 1) row_start[U_NUM] = base + incl;
}

// chunked counting-sort of edges into NB dst-buckets; coalesced run writes
__global__ __launch_bounds__(256) void k_binA(const int* __restrict__ edge,
                                              unsigned* __restrict__ gcur,
                                              uint2* __restrict__ bins) {
    __shared__ int hist[256];
    __shared__ int startx[256];
    __shared__ int cur[256];
    __shared__ int gbase[256];
    __shared__ uint2 stage[4096];
    int t = threadIdx.x;
    int base = blockIdx.x * 4096;
    hist[t] = 0; cur[t] = 0;
    __syncthreads();
    int src[16], dst[16];
#pragma unroll
    for (int j = 0; j < 16; ++j) {
        int e = base + j * 256 + t;
        src[j] = 0; dst[j] = -1;
        if (e < NE) {
            src[j] = edge[e];
            dst[j] = edge[NE + e];
            atomicAdd(&hist[dst[j] >> BSH], 1);
        }
    }
    __syncthreads();
    startx[t] = hist[t];
    __syncthreads();
    for (int off = 1; off < 256; off <<= 1) {
        int v = (t >= off) ? startx[t - off] : 0;
        __syncthreads();
        startx[t] += v;
        __syncthreads();
    }
    {
        int ex = startx[t] - hist[t];
        __syncthreads();
        startx[t] = ex;
    }
    if (t < NB) gbase[t] = (int)atomicAdd(&gcur[t], (unsigned)hist[t]);
    __syncthreads();
#pragma unroll
    for (int j = 0; j < 16; ++j) {
        if (dst[j] >= 0) {
            int b = dst[j] >> BSH;
            int p = startx[b] + atomicAdd(&cur[b], 1);
            stage[p] = make_uint2((unsigned)src[j], (unsigned)dst[j]);
        }
    }
    __syncthreads();
    int cnt = NE - base; if (cnt > 4096) cnt = 4096;
    for (int p = t; p < cnt; p += 256) {
        uint2 v = stage[p];
        int b = (int)(v.y >> BSH);
        bins[(size_t)b * BCAP + gbase[b] + (p - startx[b])] = v;
    }
}

// per-bucket CSR fill: writes confined to a ~32KB L2-resident csr window
__global__ __launch_bounds__(256) void k_fillB(const uint2* __restrict__ bins,
                                               const unsigned* __restrict__ gcur,
                                               const int* __restrict__ row_start,
                                               int* __restrict__ csr) {
    __shared__ int cur[512];
    int b = blockIdx.x, t = threadIdx.x;
    cur[t] = 0; cur[t + 256] = 0;
    __syncthreads();
    int cnt = (int)gcur[b];
    int d0 = b << BSH;
    for (int i = t; i < cnt; i += 256) {
        uint2 e = bins[(size_t)b * BCAP + i];
        int d = (int)e.y;
        int pos = row_start[d] + atomicAdd(&cur[d - d0], 1);
        csr[pos] = (int)e.x;
    }
}

// XS[r] = bf16((relu?(x[r]) @ W) * dinv[r]), MFMA version: 64 users/block
__global__ __launch_bounds__(256) void k_gemm64_mfma(
        const float* __restrict__ x, const float* __restrict__ w,
        const float* __restrict__ dinv, unsigned* __restrict__ outb, int relu_in) {
    __shared__ __align__(16) short Xa[64 * 64];
    __shared__ float dv[64];
    int t = threadIdx.x;
    int lane = t & 63, wid = t >> 6;
    int l15 = lane & 15, lg = lane >> 4;
    bf16x8 wf[2];
#pragma unroll
    for (int ks = 0; ks < 2; ++ks) {
        int col = wid * 16 + l15;
        int kb = ks * 32 + lg * 8;
        bf16x8 f;
#pragma unroll
        for (int j = 0; j < 8; ++j) f[j] = f2bf(w[(kb + j) * 64 + col]);
        wf[ks] = f;
    }
    int u0 = blockIdx.x * 64;
    {
        int ur = t >> 2, d0 = (t & 3) * 16;
        int u = u0 + ur;
        float xv[16];
        if (u < U_NUM) {
            const float4* up = (const float4*)(x + (size_t)u * 64 + d0);
#pragma unroll
            for (int q = 0; q < 4; ++q) {
                float4 v = up[q];
                xv[q * 4 + 0] = v.x; xv[q * 4 + 1] = v.y; xv[q * 4 + 2] = v.z; xv[q * 4 + 3] = v.w;
            }
        } else {
#pragma unroll
            for (int q = 0; q < 16; ++q) xv[q] = 0.f;
        }
        if (relu_in) {
#pragma unroll
            for (int q = 0; q < 16; ++q) xv[q] = fmaxf(xv[q], 0.f);
        }
        bf16x8 p0, p1;
#pragma unroll
        for (int j = 0; j < 8; ++j) { p0[j] = f2bf(xv[j]); p1[j] = f2bf(xv[8 + j]); }
        *(bf16x8*)((char*)Xa + swzo(ur, d0 * 2, 128)) = p0;
        *(bf16x8*)((char*)Xa + swzo(ur, d0 * 2 + 16, 128)) = p1;
        if (t < 64) {
            int uu = u0 + t;
            dv[t] = dinv[(uu < U_NUM) ? uu : (U_NUM - 1)];
        }
    }
    __syncthreads();
#pragma unroll
    for (int mt = 0; mt < 4; ++mt) {
        bf16x8 a0 = *(bf16x8*)((char*)Xa + swzo(mt * 16 + l15, lg * 16, 128));
        bf16x8 a1 = *(bf16x8*)((char*)Xa + swzo(mt * 16 + l15, 64 + lg * 16, 128));
        f32x4 c = {0.f, 0.f, 0.f, 0.f};
        c = __builtin_amdgcn_mfma_f32_16x16x32_bf16(a0, wf[0], c, 0, 0, 0);
        c = __builtin_amdgcn_mfma_f32_16x16x32_bf16(a1, wf[1], c, 0, 0, 0);
        int col = wid * 16 + l15;
#pragma unroll
        for (int r = 0; r < 4; ++r) {
            int row = mt * 16 + lg * 4 + r;
            float v = c[r] * dv[row];
            float other = __shfl_xor(v, 1);
            int u = u0 + row;
            if (!(l15 & 1) && u < U_NUM)
                outb[(size_t)u * 32 + (col >> 1)] = pk2(v, other);
        }
    }
}

// per dst row (one half-wave each): 8 rows per block, dense CSR stream, 8-deep load chain
__global__ __launch_bounds__(256) void k_gather2(const unsigned* __restrict__ xs, const float* __restrict__ dinv,
                                                 const int* __restrict__ row_start, const int* __restrict__ csr,
                                                 const float* __restrict__ bias, float* __restrict__ outb) {
    int lane = threadIdx.x & 63, half = lane >> 5, sl = lane & 31;
    int i = blockIdx.x * 8 + (threadIdx.x >> 6) * 2 + half;
    int s0 = row_start[i], s1 = row_start[i + 1];
    float di = dinv[i];
    unsigned pks = xs[(size_t)i * 32 + sl];
    float accx = bflo(pks), accy = bfhi(pks);
    int e = s0;
    for (; e + 8 <= s1; e += 8) {
        int id0 = csr[e], id1 = csr[e + 1], id2 = csr[e + 2], id3 = csr[e + 3];
        int id4 = csr[e + 4], id5 = csr[e + 5], id6 = csr[e + 6], id7 = csr[e + 7];
        unsigned p0 = xs[(size_t)id0 * 32 + sl];
        unsigned p1 = xs[(size_t)id1 * 32 + sl];
        unsigned p2 = xs[(size_t)id2 * 32 + sl];
        unsigned p3 = xs[(size_t)id3 * 32 + sl];
        unsigned p4 = xs[(size_t)id4 * 32 + sl];
        unsigned p5 = xs[(size_t)id5 * 32 + sl];
        unsigned p6 = xs[(size_t)id6 * 32 + sl];
        unsigned p7 = xs[(size_t)id7 * 32 + sl];
        accx += ((bflo(p0) + bflo(p1)) + (bflo(p2) + bflo(p3))) +
                ((bflo(p4) + bflo(p5)) + (bflo(p6) + bflo(p7)));
        accy += ((bfhi(p0) + bfhi(p1)) + (bfhi(p2) + bfhi(p3))) +
                ((bfhi(p4) + bfhi(p5)) + (bfhi(p6) + bfhi(p7)));
    }
    for (; e < s1; ++e) {
        unsigned pa = xs[(size_t)csr[e] * 32 + sl];
        accx += bflo(pa);
        accy += bfhi(pa);
    }
    float2 bb = *(const float2*)(bias + sl * 2);
    float2 o;
    o.x = fmaf(accx, di, bb.x);
    o.y = fmaf(accy, di, bb.y);
    *(float2*)(outb + (size_t)i * 64 + sl * 2) = o;
}

// ---------------- MFMA attention + ci2-sum (paired gathers, deferred reduction) ----------------
// Writes per-user 256B record at uefc[u*64]: uints 0..31 = uef bf16, 32..63 = ci2sum bf16.
#define AUB 32

__global__ __launch_bounds__(256, 5) void k_attn_mfma(
        const int* __restrict__ edge_user, const u32x2* __restrict__ ccp,
        const float* __restrict__ at_w, const float* __restrict__ at_b,
        const float* __restrict__ d2_w, const float* __restrict__ d2_b,
        const float* ue, unsigned* uefc) {
    __shared__ __align__(16) short CI[256 * 64];  // 32KB
    int t = threadIdx.x;
    int lane = t & 63, wid = t >> 6;
    int l15 = lane & 15, lg = lane >> 4;
    int half = lane >> 5, sl = lane & 31;

    bf16x8 bw[3][2];
#pragma unroll
    for (int nt = 0; nt < 3; ++nt) {
        int j48 = nt * 16 + l15;
        int h = j48 >> 3, kk = j48 & 7;
#pragma unroll
        for (int ks = 0; ks < 2; ++ks) {
            int kb = ks * 32 + lg * 8;
            bf16x8 f;
#pragma unroll
            for (int j = 0; j < 8; ++j) f[j] = f2bf(at_w[h * 512 + (kb + j) * 8 + kk]);
            bw[nt][ks] = f;
        }
    }
    float atbv[3], dcoef[3];
#pragma unroll
    for (int nt = 0; nt < 3; ++nt) {
        atbv[nt] = at_b[nt * 16 + l15];
        dcoef[nt] = d2_w[1 + nt * 16 + l15];
    }
    float d2w0 = d2_w[0], d2b0 = d2_b[0];

    int u0 = blockIdx.x * AUB;
    float accx[8], accy[8];
#pragma unroll
    for (int j = 0; j < 8; ++j) { accx[j] = 0.f; accy[j] = 0.f; }
#pragma unroll
    for (int j = 0; j < 8; ++j) {
#pragma unroll
        for (int q = 0; q < 4; ++q) {
            int s = q * 2 + half;
            int row = wid * 64 + j * 8 + s;
            unsigned pk = 0;
            if (s < 5) {
                int id = edge_user[U_NUM * SEQL + (u0 + wid * 8 + j) * SEQL + s];
                u32x2 pr = ccp[(size_t)id * 32 + sl];
                pk = pr.x;
                accx[j] += bflo(pr.y);
                accy[j] += bfhi(pr.y);
            }
            *(unsigned*)((char*)CI + swzo(row, sl * 4, 128)) = pk;
        }
    }
    __syncthreads();

    float evenm = (lg & 1) ? 0.f : 1.f;
    for (int mt = 0; mt < 4; ++mt) {
        int tbase = (wid * 4 + mt) * 16;
        bf16x8 a0 = *(bf16x8*)((char*)CI + swzo(tbase + l15, lg * 16, 128));
        bf16x8 a1 = *(bf16x8*)((char*)CI + swzo(tbase + l15, 64 + lg * 16, 128));
        float g0 = 0.f, g1 = 0.f, g2 = 0.f, g3 = 0.f;
#pragma unroll
        for (int nt = 0; nt < 3; ++nt) {
            f32x4 c = {0.f, 0.f, 0.f, 0.f};
            c = __builtin_amdgcn_mfma_f32_16x16x32_bf16(a0, bw[nt][0], c, 0, 0, 0);
            c = __builtin_amdgcn_mfma_f32_16x16x32_bf16(a1, bw[nt][1], c, 0, 0, 0);
            float w0 = c[0] + atbv[nt], w1 = c[1] + atbv[nt],
                  w2 = c[2] + atbv[nt], w3 = c[3] + atbv[nt];
            float e0 = __expf(1.f - __fdividef(2.f, __expf(2.f * w0) + 1.f));
            float e1 = __expf(1.f - __fdividef(2.f, __expf(2.f * w1) + 1.f));
            float e2 = __expf(1.f - __fdividef(2.f, __expf(2.f * w2) + 1.f));
            float e3 = __expf(1.f - __fdividef(2.f, __expf(2.f * w3) + 1.f));
            float partial = e0 + evenm * (e1 + e2 + e3);
            float esum = partial + __shfl_xor(partial, 16);
            float sc = __fdividef(dcoef[nt], esum);
            g0 = fmaf(e0, sc, g0);
            g1 = fmaf(e1, sc, g1);
            g2 = fmaf(e2, sc, g2);
            g3 = fmaf(e3, sc, g3);
        }
#pragma unroll
        for (int d = 1; d < 16; d <<= 1) {
            g0 += __shfl_xor(g0, d);
            g1 += __shfl_xor(g1, d);
            g2 += __shfl_xor(g2, d);
            g3 += __shfl_xor(g3, d);
        }
        float gA0 = rd_lane(g0, 0), gA1 = rd_lane(g1, 0), gA2 = rd_lane(g2, 0),
              gA3 = rd_lane(g3, 0), gA4 = rd_lane(g0, 16);
        float gB0 = rd_lane(g0, 32), gB1 = rd_lane(g1, 32), gB2 = rd_lane(g2, 32),
              gB3 = rd_lane(g3, 32), gB4 = rd_lane(g0, 48);
        float gs0 = half ? gB0 : gA0;
        float gs1 = half ? gB1 : gA1;
        float gs2 = half ? gB2 : gA2;
        float gs3 = half ? gB3 : gA3;
        float gs4 = half ? gB4 : gA4;
        int urow = tbase + half * 8;
        int u = u0 + (tbase >> 3) + half;
        float2 uev = *(const float2*)(ue + (size_t)u * 64 + sl * 2);
        float rx = fmaf(d2w0, uev.x, d2b0);
        float ry = fmaf(d2w0, uev.y, d2b0);
        unsigned c0 = *(unsigned*)((char*)CI + swzo(urow + 0, sl * 4, 128));
        unsigned c1 = *(unsigned*)((char*)CI + swzo(urow + 1, sl * 4, 128));
        unsigned c2 = *(unsigned*)((char*)CI + swzo(urow + 2, sl * 4, 128));
        unsigned c3 = *(unsigned*)((char*)CI + swzo(urow + 3, sl * 4, 128));
        unsigned c4 = *(unsigned*)((char*)CI + swzo(urow + 4, sl * 4, 128));
        rx = fmaf(gs0, bflo(c0), rx); ry = fmaf(gs0, bfhi(c0), ry);
        rx = fmaf(gs1, bflo(c1), rx); ry = fmaf(gs1, bfhi(c1), ry);
        rx = fmaf(gs2, bflo(c2), rx); ry = fmaf(gs2, bfhi(c2), ry);
        rx = fmaf(gs3, bflo(c3), rx); ry = fmaf(gs3, bfhi(c3), ry);
        rx = fmaf(gs4, bflo(c4), rx); ry = fmaf(gs4, bfhi(c4), ry);
        uefc[(size_t)u * 64 + sl] = pk2(rx, ry);
    }
#pragma unroll
    for (int j = 0; j < 8; ++j) {
        float ax = accx[j] + __shfl_xor(accx[j], 32);
        float ay = accy[j] + __shfl_xor(accy[j], 32);
        if (!half) {
            int u = u0 + wid * 8 + j;
            uefc[(size_t)u * 64 + 32 + sl] = pk2(ax, ay);
        }
    }
}

// ---------------- MFMA MLP: 1024 threads, 32 users/tile, K-split phase 2/3 ----------------
#define N_TILES2 3125

__global__ __launch_bounds__(1024, 2) void k_mlp_mfma(
        const unsigned* __restrict__ uefc,
        const float* __restrict__ w1, const float* __restrict__ b1,
        const float* __restrict__ w2, const float* __restrict__ b2,
        const float* __restrict__ w3, const float* __restrict__ b3,
        const float* __restrict__ dw, const float* __restrict__ db,
        float* __restrict__ out) {
    __shared__ __align__(16) short Xa[32 * 64];     // 4KB  stride 128B (uef)
    __shared__ __align__(16) short Ca[32 * 64];     // 4KB  stride 128B (ci2sum)
    __shared__ __align__(16) short h1a[32 * 256];   // 16KB stride 512B
    __shared__ __align__(16) short h2c[32 * 128];   // 8KB  stride 256B
    __shared__ __align__(16) float Pf[32 * 128];    // 16KB f32 partials / final out tile
    int t = threadIdx.x;
    int lane = t & 63, w = t >> 6;        // 16 waves
    int l15 = lane & 15, lg = lane >> 4;
    int nt = w & 7, kh = w >> 3;          // phases 2-3 mapping
    int col1 = w * 16 + l15;              // phase-1 column
    int col2 = nt * 16 + l15;             // phase-2/3 column

    bf16x8 wf1[2];
#pragma unroll
    for (int ks = 0; ks < 2; ++ks) {
        int kb = ks * 32 + lg * 8;
        bf16x8 f;
#pragma unroll
        for (int j = 0; j < 8; ++j) f[j] = f2bf(w1[(kb + j) * 256 + col1]);
        wf1[ks] = f;
    }
    bf16x8 wf2[4];
#pragma unroll
    for (int ks = 0; ks < 4; ++ks) {
        int kb = kh * 128 + ks * 32 + lg * 8;
        bf16x8 f;
#pragma unroll
        for (int j = 0; j < 8; ++j) f[j] = f2bf(w2[(kb + j) * 128 + col2]);
        wf2[ks] = f;
    }
    bf16x8 wf3[3];
#pragma unroll
    for (int ks = 0; ks < 3; ++ks) {
        bf16x8 f;
#pragma unroll
        for (int j = 0; j < 8; ++j) {
            int k = kh * 96 + ks * 32 + lg * 8 + j;
            float v = 0.f;
            if (col2 < 120) v = (k < 128) ? w3[k * 120 + col2] : dw[(k - 128) * 120 + col2];
            f[j] = f2bf(v);
        }
        wf3[ks] = f;
    }
    float bias1 = b1[col1];
    float bias2 = b2[col2];
    float bias3 = (col2 < 120) ? (b3[col2] + 5.f * db[col2]) : 0.f;

    int ur = t >> 5, q = t & 31;
    for (int tile = blockIdx.x; tile < N_TILES2; tile += gridDim.x) {
        int u0 = tile * 32;
        {   // phase 0: load 32 records (256B each); 32 threads x 8B per user
            const u32x2* up = (const u32x2*)(uefc + (size_t)(u0 + ur) * 64 + q * 2);
            u32x2 A = __builtin_nontemporal_load(up);
            char* base = (q < 16) ? ((char*)Xa) : ((char*)Ca);
            *(u32x2*)(base + swzo(ur, (q & 15) * 8, 128)) = A;
        }
        __syncthreads();
        // ---- phase 1: h1 = relu(X @ W1 + b1), strip per wave ----
#pragma unroll
        for (int mt = 0; mt < 2; ++mt) {
            bf16x8 a0 = *(bf16x8*)((char*)Xa + swzo(mt * 16 + l15, lg * 16, 128));
            bf16x8 a1 = *(bf16x8*)((char*)Xa + swzo(mt * 16 + l15, 64 + lg * 16, 128));
            f32x4 c = {0.f, 0.f, 0.f, 0.f};
            c = __builtin_amdgcn_mfma_f32_16x16x32_bf16(a0, wf1[0], c, 0, 0, 0);
            c = __builtin_amdgcn_mfma_f32_16x16x32_bf16(a1, wf1[1], c, 0, 0, 0);
#pragma unroll
            for (int r = 0; r < 4; ++r) {
                int row = mt * 16 + lg * 4 + r;
                *(short*)((char*)h1a + swzo(row, col1 * 2, 512)) = f2bf(fmaxf(c[r] + bias1, 0.f));
            }
        }
        __syncthreads();
        // ---- phase 2: h2 = relu(h1 @ W2 + b2), strips x K-halves ----
        f32x4 c20 = {0.f, 0.f, 0.f, 0.f}, c21 = c20;
#pragma unroll
        for (int ks = 0; ks < 4; ++ks) {
            int bc = kh * 256 + ks * 64 + lg * 16;
            bf16x8 a0 = *(bf16x8*)((char*)h1a + swzo(l15, bc, 512));
            bf16x8 a1 = *(bf16x8*)((char*)h1a + swzo(16 + l15, bc, 512));
            c20 = __builtin_amdgcn_mfma_f32_16x16x32_bf16(a0, wf2[ks], c20, 0, 0, 0);
            c21 = __builtin_amdgcn_mfma_f32_16x16x32_bf16(a1, wf2[ks], c21, 0, 0, 0);
        }
        if (kh == 0) {
#pragma unroll
            for (int r = 0; r < 4; ++r) {
                Pf[(lg * 4 + r) * 128 + col2] = c20[r];
                Pf[(16 + lg * 4 + r) * 128 + col2] = c21[r];
            }
        }
        __syncthreads();
        if (kh == 1) {
#pragma unroll
            for (int r = 0; r < 4; ++r) {
                float s0 = c20[r] + Pf[(lg * 4 + r) * 128 + col2];
                float s1 = c21[r] + Pf[(16 + lg * 4 + r) * 128 + col2];
                *(short*)((char*)h2c + swzo(lg * 4 + r, col2 * 2, 256)) = f2bf(fmaxf(s0 + bias2, 0.f));
                *(short*)((char*)h2c + swzo(16 + lg * 4 + r, col2 * 2, 256)) = f2bf(fmaxf(s1 + bias2, 0.f));
            }
        }
        __syncthreads();
        // ---- phase 3: out = [h2|ci2sum] @ [W3;dw], strips x K-halves (K=192) ----
        f32x4 c30 = {0.f, 0.f, 0.f, 0.f}, c31 = c30;
#pragma unroll
        for (int ks = 0; ks < 3; ++ks) {
            int k0 = kh * 96 + ks * 32;
            bf16x8 a0, a1;
            if (k0 < 128) {
                a0 = *(bf16x8*)((char*)h2c + swzo(l15, k0 * 2 + lg * 16, 256));
                a1 = *(bf16x8*)((char*)h2c + swzo(16 + l15, k0 * 2 + lg * 16, 256));
            } else {
                a0 = *(bf16x8*)((char*)Ca + swzo(l15, (k0 - 128) * 2 + lg * 16, 128));
                a1 = *(bf16x8*)((char*)Ca + swzo(16 + l15, (k0 - 128) * 2 + lg * 16, 128));
            }
            c30 = __builtin_amdgcn_mfma_f32_16x16x32_bf16(a0, wf3[ks], c30, 0, 0, 0);
            c31 = __builtin_amdgcn_mfma_f32_16x16x32_bf16(a1, wf3[ks], c31, 0, 0, 0);
        }
        if (kh == 0) {
#pragma unroll
            for (int r = 0; r < 4; ++r) {
                Pf[(lg * 4 + r) * 128 + col2] = c30[r];
                Pf[(16 + lg * 4 + r) * 128 + col2] = c31[r];
            }
        }
        __syncthreads();
        if (kh == 1) {
#pragma unroll
            for (int r = 0; r < 4; ++r) {
                int rowa = (lg * 4 + r) * 128 + col2;
                int rowb = (16 + lg * 4 + r) * 128 + col2;
                Pf[rowa] = c30[r] + Pf[rowa] + bias3;
                Pf[rowb] = c31[r] + Pf[rowb] + bias3;
            }
        }
        __syncthreads();
        if (t < 960) {  // writeout: 32 rows x 30 float4
            int row = t / 30, ch = t - row * 30;
            f32x4 v = *(const f32x4*)(Pf + row * 128 + ch * 4);
            __builtin_nontemporal_store(v, (f32x4*)(out + (size_t)(u0 + row) * 120 + ch * 4));
        }
        __syncthreads();
    }
}

extern "C" void kernel_launch(void* const* d_in, const int* in_sizes, int n_in,
                              void* d_out, int out_size, void* d_ws, size_t ws_size,
                              hipStream_t stream) {
    const int* edge_user   = (const int*)d_in[0];
    const int* u_v_edge    = (const int*)d_in[2];
    const float* user_table = (const float*)d_in[4];
    const float* ci_table   = (const float*)d_in[5];
    const float* ci_table2  = (const float*)d_in[6];
    const float* gcn1_w = (const float*)d_in[7];
    const float* gcn1_b = (const float*)d_in[8];
    const float* gcn2_w = (const float*)d_in[9];
    const float* gcn2_b = (const float*)d_in[10];
    const float* at_w = (const float*)d_in[11];
    const float* at_b = (const float*)d_in[12];
    const float* d2_w = (const float*)d_in[13];
    const float* d2_b = (const float*)d_in[14];
    const float* d1u_w = (const float*)d_in[15];
    const float* d1u_b = (const float*)d_in[16];
    const float* d2u_w = (const float*)d_in[17];
    const float* d2u_b = (const float*)d_in[18];
    const float* d3u_w = (const float*)d_in[19];
    const float* d3u_b = (const float*)d_in[20];
    const float* d1_w = (const float*)d_in[21];
    const float* d1_b = (const float*)d_in[22];
    float* out = (float*)d_out;
    char* ws = (char*)d_ws;

    int* deg       = (int*)(ws + OFF_DEG);
    int* row_start = (int*)(ws + OFF_ROWSTART);
    float* dinv    = (float*)(ws + OFF_DINV);
    int* bsum      = (int*)(ws + OFF_BSUM);
    int* csr       = (int*)(ws + OFF_CSR);
    unsigned* XS   = (unsigned*)(ws + OFF_XS);
    float* B       = (float*)(ws + OFF_B);
    u32x2* CCP     = (u32x2*)(ws + OFF_CCP);
    uint2* bins    = (uint2*)(ws + OFF_BINS);
    unsigned* gcur = (unsigned*)(ws + OFF_GCUR);

    (void)hipMemsetAsync(ws, 0, 400000, stream);            // deg
    (void)hipMemsetAsync(ws + OFF_GCUR, 0, NB * 4, stream); // bin cursors
    k_count<<<6250, 256, 0, stream>>>(u_v_edge, deg);
    k_cvtP<<<6250, 256, 0, stream>>>(ci_table, ci_table2, CCP);
    k_dinv<<<391, 256, 0, stream>>>(deg, dinv);
    k_scanA<<<98, 1024, 0, stream>>>(deg, bsum);
    k_scanB<<<1, 64, 0, stream>>>(bsum, 98);
    k_scanC<<<98, 1024, 0, stream>>>(deg, bsum, row_start);
    k_binA<<<391, 256, 0, stream>>>(u_v_edge, gcur, bins);
    k_fillB<<<NB, 256, 0, stream>>>(bins, gcur, row_start, csr);

    // GCN layer 1
    k_gemm64_mfma<<<1563, 256, 0, stream>>>(user_table, gcn1_w, dinv, XS, 0);
    k_gather2<<<12500, 256, 0, stream>>>(XS, dinv, row_start, csr, gcn1_b, B);
    // GCN layer 2
    k_gemm64_mfma<<<1563, 256, 0, stream>>>(B, gcn2_w, dinv, XS, 1);
    k_gather2<<<12500, 256, 0, stream>>>(XS, dinv, row_start, csr, gcn2_b, B);

    // MFMA attention + ci2sum -> per-user [uef|ci2s] records (in-place over ue)
    k_attn_mfma<<<3125, 256, 0, stream>>>(edge_user, CCP, at_w, at_b, d2_w, d2_b,
                                          B, (unsigned*)B);
    // MFMA MLP + score2 (16-wave, K-split)
    k_mlp_mfma<<<512, 1024, 0, stream>>>((const unsigned*)B,
                                         d1u_w, d1u_b, d2u_w, d2u_b, d3u_w, d3u_b, d1_w, d1_b, out);
}

// Round 19
// 396.184 us; speedup vs baseline: 1.0843x; 1.0843x over previous
//
#include <hip/hip_runtime.h>

#define U_NUM 100000
#define NE    1600000
#define SEQL  5

// ws layout (bytes)
#define OFF_DEG      0UL         // int[100000]
#define OFF_ROWSTART 800000UL    // int[100001]
#define OFF_DINV     1200016UL   // float[100000]
#define OFF_BSUM     1600016UL   // int[128]
#define OFF_CSR      1600528UL   // int[1600000]
#define OFF_XS       8000528UL   // bf16-packed uint[3200000] (12.8MB); bins overlay pre-gemm
#define OFF_B        20800528UL  // float[6400000] (25.6MB); attn rewrites as [uef|ci2s] bf16 records
#define OFF_CCP      46400528UL  // u32x2[1600000]: paired {ci,ci2} bf16 rows (12.8MB, end 59200528)

// edge binning (bins overlay XS region; dead before k_gemm64_mfma writes XS)
#define NB    196
#define BSH   9
#define BCAP  12240
#define OFF_BINS  OFF_XS
#define OFF_GCUR  (OFF_BINS + (size_t)NB * BCAP * 8)

typedef __attribute__((ext_vector_type(8))) short bf16x8;
typedef __attribute__((ext_vector_type(4))) float f32x4;
typedef __attribute__((ext_vector_type(2))) unsigned u32x2;

__device__ __forceinline__ float rd_lane(float v, int l) {
    return __int_as_float(__builtin_amdgcn_readlane(__float_as_int(v), l));
}

__device__ __forceinline__ short f2bf(float f) {
    unsigned u = __float_as_uint(f);
    unsigned r = (u + 0x7fffu + ((u >> 16) & 1u)) >> 16;
    return (short)r;
}

__device__ __forceinline__ unsigned pk2(float a, float b) {
    return ((unsigned)(unsigned short)f2bf(a)) | (((unsigned)(unsigned short)f2bf(b)) << 16);
}

__device__ __forceinline__ float bflo(unsigned p) { return __uint_as_float(p << 16); }
__device__ __forceinline__ float bfhi(unsigned p) { return __uint_as_float(p & 0xffff0000u); }

// swizzled byte offset within a row-major LDS tile (T2: XOR bits 4-6 by row&7)
__device__ __forceinline__ int swzo(int row, int bytecol, int rowstride) {
    return row * rowstride + (bytecol ^ ((row & 7) << 4));
}

__global__ __launch_bounds__(256) void k_count(const int* __restrict__ edge, int* __restrict__ deg) {
    int e = blockIdx.x * 256 + threadIdx.x;
    atomicAdd(&deg[edge[NE + e]], 1);
}

__global__ __launch_bounds__(256) void k_dinv(const int* __restrict__ deg, float* __restrict__ dinv) {
    int i = blockIdx.x * 256 + threadIdx.x;
    if (i < U_NUM) dinv[i] = rsqrtf((float)(deg[i] + 1));
}

// paired conversion: CCP[i] = {pk2(ci[2i],ci[2i+1]), pk2(ci2[2i],ci2[2i+1])}, i over 1.6M
__global__ __launch_bounds__(256) void k_cvtP(const float* __restrict__ ci, const float* __restrict__ ci2,
                                              u32x2* __restrict__ ccp) {
    int i = blockIdx.x * 256 + threadIdx.x;
    float2 a = *(const float2*)(ci + (size_t)i * 2);
    float2 b = *(const float2*)(ci2 + (size_t)i * 2);
    u32x2 r;
    r.x = pk2(a.x, a.y);
    r.y = pk2(b.x, b.y);
    ccp[i] = r;
}

__global__ __launch_bounds__(1024) void k_scanA(const int* __restrict__ deg, int* __restrict__ bsum) {
    __shared__ int sm[1024];
    int i = blockIdx.x * 1024 + threadIdx.x;
    sm[threadIdx.x] = (i < U_NUM) ? deg[i] : 0;
    __syncthreads();
    for (int off = 512; off > 0; off >>= 1) {
        if (threadIdx.x < off) sm[threadIdx.x] += sm[threadIdx.x + off];
        __syncthreads();
    }
    if (threadIdx.x == 0) bsum[blockIdx.x] = sm[0];
}

__global__ void k_scanB(int* bsum, int nb) {
    if (threadIdx.x == 0) {
        int acc = 0;
        for (int b = 0; b < nb; ++b) { int v = bsum[b]; bsum[b] = acc; acc += v; }
    }
}

__global__ __launch_bounds__(1024) void k_scanC(const int* __restrict__ deg, const int* __restrict__ bsum,
                                                int* __restrict__ row_start) {
    __shared__ int sm[1024];
    int t = threadIdx.x;
    int i = blockIdx.x * 1024 + t;
    int v = (i < U_NUM) ? deg[i] : 0;
    sm[t] = v;
    __syncthreads();
    for (int off = 1; off < 1024; off <<= 1) {
        int x = (t >= off) ? sm[t - off] : 0;
        __syncthreads();
        sm[t] += x;
        __syncthreads();
    }
    int incl = sm[t];
    int base = bsum[blockIdx.x];
    if (i < U_NUM) row_start[i] = base + incl - v;
    if (i == U_NUM - 1) row_start[U_NUM] = base + incl;
}

// chunked counting-sort of edges into NB dst-buckets; coalesced run writes
__global__ __launch_bounds__(256) void k_binA(const int* __restrict__ edge,
                                              unsigned* __restrict__ gcur,
                                              uint2* __restrict__ bins) {
    __shared__ int hist[256];
    __shared__ int startx[256];
    __shared__ int cur[256];
    __shared__ int gbase[256];
    __shared__ uint2 stage[4096];
    int t = threadIdx.x;
    int base = blockIdx.x * 4096;
    hist[t] = 0; cur[t] = 0;
    __syncthreads();
    int src[16], dst[16];
#pragma unroll
    for (int j = 0; j < 16; ++j) {
        int e = base + j * 256 + t;
        src[j] = 0; dst[j] = -1;
        if (e < NE) {
            src[j] = edge[e];
            dst[j] = edge[NE + e];
            atomicAdd(&hist[dst[j] >> BSH], 1);
        }
    }
    __syncthreads();
    startx[t] = hist[t];
    __syncthreads();
    for (int off = 1; off < 256; off <<= 1) {
        int v = (t >= off) ? startx[t - off] : 0;
        __syncthreads();
        startx[t] += v;
        __syncthreads();
    }
    {
        int ex = startx[t] - hist[t];
        __syncthreads();
        startx[t] = ex;
    }
    if (t < NB) gbase[t] = (int)atomicAdd(&gcur[t], (unsigned)hist[t]);
    __syncthreads();
#pragma unroll
    for (int j = 0; j < 16; ++j) {
        if (dst[j] >= 0) {
            int b = dst[j] >> BSH;
            int p = startx[b] + atomicAdd(&cur[b], 1);
            stage[p] = make_uint2((unsigned)src[j], (unsigned)dst[j]);
        }
    }
    __syncthreads();
    int cnt = NE - base; if (cnt > 4096) cnt = 4096;
    for (int p = t; p < cnt; p += 256) {
        uint2 v = stage[p];
        int b = (int)(v.y >> BSH);
        bins[(size_t)b * BCAP + gbase[b] + (p - startx[b])] = v;
    }
}

// per-bucket CSR fill: writes confined to a ~32KB L2-resident csr window
__global__ __launch_bounds__(256) void k_fillB(const uint2* __restrict__ bins,
                                               const unsigned* __restrict__ gcur,
                                               const int* __restrict__ row_start,
                                               int* __restrict__ csr) {
    __shared__ int cur[512];
    int b = blockIdx.x, t = threadIdx.x;
    cur[t] = 0; cur[t + 256] = 0;
    __syncthreads();
    int cnt = (int)gcur[b];
    int d0 = b << BSH;
    for (int i = t; i < cnt; i += 256) {
        uint2 e = bins[(size_t)b * BCAP + i];
        int d = (int)e.y;
        int pos = row_start[d] + atomicAdd(&cur[d - d0], 1);
        csr[pos] = (int)e.x;
    }
}

// XS[r] = bf16((relu?(x[r]) @ W) * dinv[r]), MFMA version: 64 users/block
__global__ __launch_bounds__(256) void k_gemm64_mfma(
        const float* __restrict__ x, const float* __restrict__ w,
        const float* __restrict__ dinv, unsigned* __restrict__ outb, int relu_in) {
    __shared__ __align__(16) short Xa[64 * 64];
    __shared__ float dv[64];
    int t = threadIdx.x;
    int lane = t & 63, wid = t >> 6;
    int l15 = lane & 15, lg = lane >> 4;
    bf16x8 wf[2];
#pragma unroll
    for (int ks = 0; ks < 2; ++ks) {
        int col = wid * 16 + l15;
        int kb = ks * 32 + lg * 8;
        bf16x8 f;
#pragma unroll
        for (int j = 0; j < 8; ++j) f[j] = f2bf(w[(kb + j) * 64 + col]);
        wf[ks] = f;
    }
    int u0 = blockIdx.x * 64;
    {
        int ur = t >> 2, d0 = (t & 3) * 16;
        int u = u0 + ur;
        float xv[16];
        if (u < U_NUM) {
            const float4* up = (const float4*)(x + (size_t)u * 64 + d0);
#pragma unroll
            for (int q = 0; q < 4; ++q) {
                float4 v = up[q];
                xv[q * 4 + 0] = v.x; xv[q * 4 + 1] = v.y; xv[q * 4 + 2] = v.z; xv[q * 4 + 3] = v.w;
            }
        } else {
#pragma unroll
            for (int q = 0; q < 16; ++q) xv[q] = 0.f;
        }
        if (relu_in) {
#pragma unroll
            for (int q = 0; q < 16; ++q) xv[q] = fmaxf(xv[q], 0.f);
        }
        bf16x8 p0, p1;
#pragma unroll
        for (int j = 0; j < 8; ++j) { p0[j] = f2bf(xv[j]); p1[j] = f2bf(xv[8 + j]); }
        *(bf16x8*)((char*)Xa + swzo(ur, d0 * 2, 128)) = p0;
        *(bf16x8*)((char*)Xa + swzo(ur, d0 * 2 + 16, 128)) = p1;
        if (t < 64) {
            int uu = u0 + t;
            dv[t] = dinv[(uu < U_NUM) ? uu : (U_NUM - 1)];
        }
    }
    __syncthreads();
#pragma unroll
    for (int mt = 0; mt < 4; ++mt) {
        bf16x8 a0 = *(bf16x8*)((char*)Xa + swzo(mt * 16 + l15, lg * 16, 128));
        bf16x8 a1 = *(bf16x8*)((char*)Xa + swzo(mt * 16 + l15, 64 + lg * 16, 128));
        f32x4 c = {0.f, 0.f, 0.f, 0.f};
        c = __builtin_amdgcn_mfma_f32_16x16x32_bf16(a0, wf[0], c, 0, 0, 0);
        c = __builtin_amdgcn_mfma_f32_16x16x32_bf16(a1, wf[1], c, 0, 0, 0);
        int col = wid * 16 + l15;
#pragma unroll
        for (int r = 0; r < 4; ++r) {
            int row = mt * 16 + lg * 4 + r;
            float v = c[r] * dv[row];
            float other = __shfl_xor(v, 1);
            int u = u0 + row;
            if (!(l15 & 1) && u < U_NUM)
                outb[(size_t)u * 32 + (col >> 1)] = pk2(v, other);
        }
    }
}

// per dst row (one half-wave each): 8 rows per block, dense CSR stream, 8-deep load chain
__global__ __launch_bounds__(256) void k_gather2(const unsigned* __restrict__ xs, const float* __restrict__ dinv,
                                                 const int* __restrict__ row_start, const int* __restrict__ csr,
                                                 const float* __restrict__ bias, float* __restrict__ outb) {
    int lane = threadIdx.x & 63, half = lane >> 5, sl = lane & 31;
    int i = blockIdx.x * 8 + (threadIdx.x >> 6) * 2 + half;
    int s0 = row_start[i], s1 = row_start[i + 1];
    float di = dinv[i];
    unsigned pks = xs[(size_t)i * 32 + sl];
    float accx = bflo(pks), accy = bfhi(pks);
    int e = s0;
    for (; e + 8 <= s1; e += 8) {
        int id0 = csr[e], id1 = csr[e + 1], id2 = csr[e + 2], id3 = csr[e + 3];
        int id4 = csr[e + 4], id5 = csr[e + 5], id6 = csr[e + 6], id7 = csr[e + 7];
        unsigned p0 = xs[(size_t)id0 * 32 + sl];
        unsigned p1 = xs[(size_t)id1 * 32 + sl];
        unsigned p2 = xs[(size_t)id2 * 32 + sl];
        unsigned p3 = xs[(size_t)id3 * 32 + sl];
        unsigned p4 = xs[(size_t)id4 * 32 + sl];
        unsigned p5 = xs[(size_t)id5 * 32 + sl];
        unsigned p6 = xs[(size_t)id6 * 32 + sl];
        unsigned p7 = xs[(size_t)id7 * 32 + sl];
        accx += ((bflo(p0) + bflo(p1)) + (bflo(p2) + bflo(p3))) +
                ((bflo(p4) + bflo(p5)) + (bflo(p6) + bflo(p7)));
        accy += ((bfhi(p0) + bfhi(p1)) + (bfhi(p2) + bfhi(p3))) +
                ((bfhi(p4) + bfhi(p5)) + (bfhi(p6) + bfhi(p7)));
    }
    for (; e < s1; ++e) {
        unsigned pa = xs[(size_t)csr[e] * 32 + sl];
        accx += bflo(pa);
        accy += bfhi(pa);
    }
    float2 bb = *(const float2*)(bias + sl * 2);
    float2 o;
    o.x = fmaf(accx, di, bb.x);
    o.y = fmaf(accy, di, bb.y);
    *(float2*)(outb + (size_t)i * 64 + sl * 2) = o;
}

// ---------------- MFMA attention + ci2-sum (paired gathers, deferred reduction) ----------------
// Writes per-user 256B record at uefc[u*64]: uints 0..31 = uef bf16, 32..63 = ci2sum bf16.
#define AUB 32

__global__ __launch_bounds__(256) void k_attn_mfma(
        const int* __restrict__ edge_user, const u32x2* __restrict__ ccp,
        const float* __restrict__ at_w, const float* __restrict__ at_b,
        const float* __restrict__ d2_w, const float* __restrict__ d2_b,
        const float* ue, unsigned* uefc) {
    __shared__ __align__(16) short CI[256 * 64];  // 32KB
    int t = threadIdx.x;
    int lane = t & 63, wid = t >> 6;
    int l15 = lane & 15, lg = lane >> 4;
    int half = lane >> 5, sl = lane & 31;

    bf16x8 bw[3][2];
#pragma unroll
    for (int nt = 0; nt < 3; ++nt) {
        int j48 = nt * 16 + l15;
        int h = j48 >> 3, kk = j48 & 7;
#pragma unroll
        for (int ks = 0; ks < 2; ++ks) {
            int kb = ks * 32 + lg * 8;
            bf16x8 f;
#pragma unroll
            for (int j = 0; j < 8; ++j) f[j] = f2bf(at_w[h * 512 + (kb + j) * 8 + kk]);
            bw[nt][ks] = f;
        }
    }
    float atbv[3], dcoef[3];
#pragma unroll
    for (int nt = 0; nt < 3; ++nt) {
        atbv[nt] = at_b[nt * 16 + l15];
        dcoef[nt] = d2_w[1 + nt * 16 + l15];
    }
    float d2w0 = d2_w[0], d2b0 = d2_b[0];

    int u0 = blockIdx.x * AUB;
    float accx[8], accy[8];
#pragma unroll
    for (int j = 0; j < 8; ++j) { accx[j] = 0.f; accy[j] = 0.f; }
#pragma unroll
    for (int j = 0; j < 8; ++j) {
#pragma unroll
        for (int q = 0; q < 4; ++q) {
            int s = q * 2 + half;
            int row = wid * 64 + j * 8 + s;
            unsigned pk = 0;
            if (s < 5) {
                int id = edge_user[U_NUM * SEQL + (u0 + wid * 8 + j) * SEQL + s];
                u32x2 pr = ccp[(size_t)id * 32 + sl];
                pk = pr.x;
                accx[j] += bflo(pr.y);
                accy[j] += bfhi(pr.y);
            }
            *(unsigned*)((char*)CI + swzo(row, sl * 4, 128)) = pk;
        }
    }
    __syncthreads();

    float evenm = (lg & 1) ? 0.f : 1.f;
    for (int mt = 0; mt < 4; ++mt) {
        int tbase = (wid * 4 + mt) * 16;
        bf16x8 a0 = *(bf16x8*)((char*)CI + swzo(tbase + l15, lg * 16, 128));
        bf16x8 a1 = *(bf16x8*)((char*)CI + swzo(tbase + l15, 64 + lg * 16, 128));
        float g0 = 0.f, g1 = 0.f, g2 = 0.f, g3 = 0.f;
#pragma unroll
        for (int nt = 0; nt < 3; ++nt) {
            f32x4 c = {0.f, 0.f, 0.f, 0.f};
            c = __builtin_amdgcn_mfma_f32_16x16x32_bf16(a0, bw[nt][0], c, 0, 0, 0);
            c = __builtin_amdgcn_mfma_f32_16x16x32_bf16(a1, bw[nt][1], c, 0, 0, 0);
            float w0 = c[0] + atbv[nt], w1 = c[1] + atbv[nt],
                  w2 = c[2] + atbv[nt], w3 = c[3] + atbv[nt];
            float e0 = __expf(1.f - __fdividef(2.f, __expf(2.f * w0) + 1.f));
            float e1 = __expf(1.f - __fdividef(2.f, __expf(2.f * w1) + 1.f));
            float e2 = __expf(1.f - __fdividef(2.f, __expf(2.f * w2) + 1.f));
            float e3 = __expf(1.f - __fdividef(2.f, __expf(2.f * w3) + 1.f));
            float partial = e0 + evenm * (e1 + e2 + e3);
            float esum = partial + __shfl_xor(partial, 16);
            float sc = __fdividef(dcoef[nt], esum);
            g0 = fmaf(e0, sc, g0);
            g1 = fmaf(e1, sc, g1);
            g2 = fmaf(e2, sc, g2);
            g3 = fmaf(e3, sc, g3);
        }
#pragma unroll
        for (int d = 1; d < 16; d <<= 1) {
            g0 += __shfl_xor(g0, d);
            g1 += __shfl_xor(g1, d);
            g2 += __shfl_xor(g2, d);
            g3 += __shfl_xor(g3, d);
        }
        float gA0 = rd_lane(g0, 0), gA1 = rd_lane(g1, 0), gA2 = rd_lane(g2, 0),
              gA3 = rd_lane(g3, 0), gA4 = rd_lane(g0, 16);
        float gB0 = rd_lane(g0, 32), gB1 = rd_lane(g1, 32), gB2 = rd_lane(g2, 32),
              gB3 = rd_lane(g3, 32), gB4 = rd_lane(g0, 48);
        float gs0 = half ? gB0 : gA0;
        float gs1 = half ? gB1 : gA1;
        float gs2 = half ? gB2 : gA2;
        float gs3 = half ? gB3 : gA3;
        float gs4 = half ? gB4 : gA4;
        int urow = tbase + half * 8;
        int u = u0 + (tbase >> 3) + half;
        float2 uev = *(const float2*)(ue + (size_t)u * 64 + sl * 2);
        float rx = fmaf(d2w0, uev.x, d2b0);
        float ry = fmaf(d2w0, uev.y, d2b0);
        unsigned c0 = *(unsigned*)((char*)CI + swzo(urow + 0, sl * 4, 128));
        unsigned c1 = *(unsigned*)((char*)CI + swzo(urow + 1, sl * 4, 128));
        unsigned c2 = *(unsigned*)((char*)CI + swzo(urow + 2, sl * 4, 128));
        unsigned c3 = *(unsigned*)((char*)CI + swzo(urow + 3, sl * 4, 128));
        unsigned c4 = *(unsigned*)((char*)CI + swzo(urow + 4, sl * 4, 128));
        rx = fmaf(gs0, bflo(c0), rx); ry = fmaf(gs0, bfhi(c0), ry);
        rx = fmaf(gs1, bflo(c1), rx); ry = fmaf(gs1, bfhi(c1), ry);
        rx = fmaf(gs2, bflo(c2), rx); ry = fmaf(gs2, bfhi(c2), ry);
        rx = fmaf(gs3, bflo(c3), rx); ry = fmaf(gs3, bfhi(c3), ry);
        rx = fmaf(gs4, bflo(c4), rx); ry = fmaf(gs4, bfhi(c4), ry);
        uefc[(size_t)u * 64 + sl] = pk2(rx, ry);
    }
#pragma unroll
    for (int j = 0; j < 8; ++j) {
        float ax = accx[j] + __shfl_xor(accx[j], 32);
        float ay = accy[j] + __shfl_xor(accy[j], 32);
        if (!half) {
            int u = u0 + wid * 8 + j;
            uefc[(size_t)u * 64 + 32 + sl] = pk2(ax, ay);
        }
    }
}

// ---------------- MFMA MLP: 1024 threads, 32 users/tile, K-split phase 2/3 ----------------
#define N_TILES2 3125

__global__ __launch_bounds__(1024, 2) void k_mlp_mfma(
        const unsigned* __restrict__ uefc,
        const float* __restrict__ w1, const float* __restrict__ b1,
        const float* __restrict__ w2, const float* __restrict__ b2,
        const float* __restrict__ w3, const float* __restrict__ b3,
        const float* __restrict__ dw, const float* __restrict__ db,
        float* __restrict__ out) {
    __shared__ __align__(16) short Xa[32 * 64];     // 4KB  stride 128B (uef)
    __shared__ __align__(16) short Ca[32 * 64];     // 4KB  stride 128B (ci2sum)
    __shared__ __align__(16) short h1a[32 * 256];   // 16KB stride 512B
    __shared__ __align__(16) short h2c[32 * 128];   // 8KB  stride 256B
    __shared__ __align__(16) float Pf[32 * 128];    // 16KB f32 partials / final out tile
    int t = threadIdx.x;
    int lane = t & 63, w = t >> 6;        // 16 waves
    int l15 = lane & 15, lg = lane >> 4;
    int nt = w & 7, kh = w >> 3;          // phases 2-3 mapping
    int col1 = w * 16 + l15;              // phase-1 column
    int col2 = nt * 16 + l15;             // phase-2/3 column

    bf16x8 wf1[2];
#pragma unroll
    for (int ks = 0; ks < 2; ++ks) {
        int kb = ks * 32 + lg * 8;
        bf16x8 f;
#pragma unroll
        for (int j = 0; j < 8; ++j) f[j] = f2bf(w1[(kb + j) * 256 + col1]);
        wf1[ks] = f;
    }
    bf16x8 wf2[4];
#pragma unroll
    for (int ks = 0; ks < 4; ++ks) {
        int kb = kh * 128 + ks * 32 + lg * 8;
        bf16x8 f;
#pragma unroll
        for (int j = 0; j < 8; ++j) f[j] = f2bf(w2[(kb + j) * 128 + col2]);
        wf2[ks] = f;
    }
    bf16x8 wf3[3];
#pragma unroll
    for (int ks = 0; ks < 3; ++ks) {
        bf16x8 f;
#pragma unroll
        for (int j = 0; j < 8; ++j) {
            int k = kh * 96 + ks * 32 + lg * 8 + j;
            float v = 0.f;
            if (col2 < 120) v = (k < 128) ? w3[k * 120 + col2] : dw[(k - 128) * 120 + col2];
            f[j] = f2bf(v);
        }
        wf3[ks] = f;
    }
    float bias1 = b1[col1];
    float bias2 = b2[col2];
    float bias3 = (col2 < 120) ? (b3[col2] + 5.f * db[col2]) : 0.f;

    int ur = t >> 5, q = t & 31;
    for (int tile = blockIdx.x; tile < N_TILES2; tile += gridDim.x) {
        int u0 = tile * 32;
        {   // phase 0: load 32 records (256B each); 32 threads x 8B per user
            const u32x2* up = (const u32x2*)(uefc + (size_t)(u0 + ur) * 64 + q * 2);
            u32x2 A = __builtin_nontemporal_load(up);
            char* base = (q < 16) ? ((char*)Xa) : ((char*)Ca);
            *(u32x2*)(base + swzo(ur, (q & 15) * 8, 128)) = A;
        }
        __syncthreads();
        // ---- phase 1: h1 = relu(X @ W1 + b1), strip per wave ----
#pragma unroll
        for (int mt = 0; mt < 2; ++mt) {
            bf16x8 a0 = *(bf16x8*)((char*)Xa + swzo(mt * 16 + l15, lg * 16, 128));
            bf16x8 a1 = *(bf16x8*)((char*)Xa + swzo(mt * 16 + l15, 64 + lg * 16, 128));
            f32x4 c = {0.f, 0.f, 0.f, 0.f};
            c = __builtin_amdgcn_mfma_f32_16x16x32_bf16(a0, wf1[0], c, 0, 0, 0);
            c = __builtin_amdgcn_mfma_f32_16x16x32_bf16(a1, wf1[1], c, 0, 0, 0);
#pragma unroll
            for (int r = 0; r < 4; ++r) {
                int row = mt * 16 + lg * 4 + r;
                *(short*)((char*)h1a + swzo(row, col1 * 2, 512)) = f2bf(fmaxf(c[r] + bias1, 0.f));
            }
        }
        __syncthreads();
        // ---- phase 2: h2 = relu(h1 @ W2 + b2), strips x K-halves ----
        f32x4 c20 = {0.f, 0.f, 0.f, 0.f}, c21 = c20;
#pragma unroll
        for (int ks = 0; ks < 4; ++ks) {
            int bc = kh * 256 + ks * 64 + lg * 16;
            bf16x8 a0 = *(bf16x8*)((char*)h1a + swzo(l15, bc, 512));
            bf16x8 a1 = *(bf16x8*)((char*)h1a + swzo(16 + l15, bc, 512));
            c20 = __builtin_amdgcn_mfma_f32_16x16x32_bf16(a0, wf2[ks], c20, 0, 0, 0);
            c21 = __builtin_amdgcn_mfma_f32_16x16x32_bf16(a1, wf2[ks], c21, 0, 0, 0);
        }
        if (kh == 0) {
#pragma unroll
            for (int r = 0; r < 4; ++r) {
                Pf[(lg * 4 + r) * 128 + col2] = c20[r];
                Pf[(16 + lg * 4 + r) * 128 + col2] = c21[r];
            }
        }
        __syncthreads();
        if (kh == 1) {
#pragma unroll
            for (int r = 0; r < 4; ++r) {
                float s0 = c20[r] + Pf[(lg * 4 + r) * 128 + col2];
                float s1 = c21[r] + Pf[(16 + lg * 4 + r) * 128 + col2];
                *(short*)((char*)h2c + swzo(lg * 4 + r, col2 * 2, 256)) = f2bf(fmaxf(s0 + bias2, 0.f));
                *(short*)((char*)h2c + swzo(16 + lg * 4 + r, col2 * 2, 256)) = f2bf(fmaxf(s1 + bias2, 0.f));
            }
        }
        __syncthreads();
        // ---- phase 3: out = [h2|ci2sum] @ [W3;dw], strips x K-halves (K=192) ----
        f32x4 c30 = {0.f, 0.f, 0.f, 0.f}, c31 = c30;
#pragma unroll
        for (int ks = 0; ks < 3; ++ks) {
            int k0 = kh * 96 + ks * 32;
            bf16x8 a0, a1;
            if (k0 < 128) {
                a0 = *(bf16x8*)((char*)h2c + swzo(l15, k0 * 2 + lg * 16, 256));
                a1 = *(bf16x8*)((char*)h2c + swzo(16 + l15, k0 * 2 + lg * 16, 256));
            } else {
                a0 = *(bf16x8*)((char*)Ca + swzo(l15, (k0 - 128) * 2 + lg * 16, 128));
                a1 = *(bf16x8*)((char*)Ca + swzo(16 + l15, (k0 - 128) * 2 + lg * 16, 128));
            }
            c30 = __builtin_amdgcn_mfma_f32_16x16x32_bf16(a0, wf3[ks], c30, 0, 0, 0);
            c31 = __builtin_amdgcn_mfma_f32_16x16x32_bf16(a1, wf3[ks], c31, 0, 0, 0);
        }
        if (kh == 0) {
#pragma unroll
            for (int r = 0; r < 4; ++r) {
                Pf[(lg * 4 + r) * 128 + col2] = c30[r];
                Pf[(16 + lg * 4 + r) * 128 + col2] = c31[r];
            }
        }
        __syncthreads();
        if (kh == 1) {
#pragma unroll
            for (int r = 0; r < 4; ++r) {
                int rowa = (lg * 4 + r) * 128 + col2;
                int rowb = (16 + lg * 4 + r) * 128 + col2;
                Pf[rowa] = c30[r] + Pf[rowa] + bias3;
                Pf[rowb] = c31[r] + Pf[rowb] + bias3;
            }
        }
        __syncthreads();
        if (t < 960) {  // writeout: 32 rows x 30 float4
            int row = t / 30, ch = t - row * 30;
            f32x4 v = *(const f32x4*)(Pf + row * 128 + ch * 4);
            __builtin_nontemporal_store(v, (f32x4*)(out + (size_t)(u0 + row) * 120 + ch * 4));
        }
        __syncthreads();
    }
}

extern "C" void kernel_launch(void* const* d_in, const int* in_sizes, int n_in,
                              void* d_out, int out_size, void* d_ws, size_t ws_size,
                              hipStream_t stream) {
    const int* edge_user   = (const int*)d_in[0];
    const int* u_v_edge    = (const int*)d_in[2];
    const float* user_table = (const float*)d_in[4];
    const float* ci_table   = (const float*)d_in[5];
    const float* ci_table2  = (const float*)d_in[6];
    const float* gcn1_w = (const float*)d_in[7];
    const float* gcn1_b = (const float*)d_in[8];
    const float* gcn2_w = (const float*)d_in[9];
    const float* gcn2_b = (const float*)d_in[10];
    const float* at_w = (const float*)d_in[11];
    const float* at_b = (const float*)d_in[12];
    const float* d2_w = (const float*)d_in[13];
    const float* d2_b = (const float*)d_in[14];
    const float* d1u_w = (const float*)d_in[15];
    const float* d1u_b = (const float*)d_in[16];
    const float* d2u_w = (const float*)d_in[17];
    const float* d2u_b = (const float*)d_in[18];
    const float* d3u_w = (const float*)d_in[19];
    const float* d3u_b = (const float*)d_in[20];
    const float* d1_w = (const float*)d_in[21];
    const float* d1_b = (const float*)d_in[22];
    float* out = (float*)d_out;
    char* ws = (char*)d_ws;

    int* deg       = (int*)(ws + OFF_DEG);
    int* row_start = (int*)(ws + OFF_ROWSTART);
    float* dinv    = (float*)(ws + OFF_DINV);
    int* bsum      = (int*)(ws + OFF_BSUM);
    int* csr       = (int*)(ws + OFF_CSR);
    unsigned* XS   = (unsigned*)(ws + OFF_XS);
    float* B       = (float*)(ws + OFF_B);
    u32x2* CCP     = (u32x2*)(ws + OFF_CCP);
    uint2* bins    = (uint2*)(ws + OFF_BINS);
    unsigned* gcur = (unsigned*)(ws + OFF_GCUR);

    (void)hipMemsetAsync(ws, 0, 400000, stream);            // deg
    (void)hipMemsetAsync(ws + OFF_GCUR, 0, NB * 4, stream); // bin cursors
    k_count<<<6250, 256, 0, stream>>>(u_v_edge, deg);
    k_cvtP<<<6250, 256, 0, stream>>>(ci_table, ci_table2, CCP);
    k_dinv<<<391, 256, 0, stream>>>(deg, dinv);
    k_scanA<<<98, 1024, 0, stream>>>(deg, bsum);
    k_scanB<<<1, 64, 0, stream>>>(bsum, 98);
    k_scanC<<<98, 1024, 0, stream>>>(deg, bsum, row_start);
    k_binA<<<391, 256, 0, stream>>>(u_v_edge, gcur, bins);
    k_fillB<<<NB, 256, 0, stream>>>(bins, gcur, row_start, csr);

    // GCN layer 1
    k_gemm64_mfma<<<1563, 256, 0, stream>>>(user_table, gcn1_w, dinv, XS, 0);
    k_gather2<<<12500, 256, 0, stream>>>(XS, dinv, row_start, csr, gcn1_b, B);
    // GCN layer 2
    k_gemm64_mfma<<<1563, 256, 0, stream>>>(B, gcn2_w, dinv, XS, 1);
    k_gather2<<<12500, 256, 0, stream>>>(XS, dinv, row_start, csr, gcn2_b, B);

    // MFMA attention + ci2sum -> per-user [uef|ci2s] records (in-place over ue)
    k_attn_mfma<<<3125, 256, 0, stream>>>(edge_user, CCP, at_w, at_b, d2_w, d2_b,
                                          B, (unsigned*)B);
    // MFMA MLP + score2 (16-wave, K-split)
    k_mlp_mfma<<<512, 1024, 0, stream>>>((const unsigned*)B,
                                         d1u_w, d1u_b, d2u_w, d2u_b, d3u_w, d3u_b, d1_w, d1_b, out);
}